// Round 1
// baseline (492.423 us; speedup 1.0000x reference)
//
#include <hip/hip_runtime.h>

#define D 128
#define NEG_SLOPE 0.2f

typedef __attribute__((ext_vector_type(8))) short short8;
typedef __attribute__((ext_vector_type(4))) float f32x4;

__device__ __forceinline__ float wred_sum(float v){
#pragma unroll
  for (int m = 32; m; m >>= 1) v += __shfl_xor(v, m);
  return v;
}
__device__ __forceinline__ float wred_max(float v){
#pragma unroll
  for (int m = 32; m; m >>= 1) v = fmaxf(v, __shfl_xor(v, m));
  return v;
}
__device__ __forceinline__ unsigned short bf16r(float f){
  unsigned int u = __float_as_uint(f);
  u += 0x7fffu + ((u >> 16) & 1u);
  return (unsigned short)(u >> 16);
}

// K1: xn = LN(x, ln1) -> bf16  (one wave per row)
__global__ void k_ln1(const float* __restrict__ x, const float* __restrict__ g,
                      const float* __restrict__ b, unsigned short* __restrict__ xnq, int N){
  int w = (blockIdx.x * blockDim.x + threadIdx.x) >> 6;
  int lane = threadIdx.x & 63;
  if (w >= N) return;
  float2 v = *(const float2*)(x + (size_t)w * D + lane * 2);
  float mu = wred_sum(v.x + v.y) * (1.0f / D);
  float d0 = v.x - mu, d1 = v.y - mu;
  float var = wred_sum(d0 * d0 + d1 * d1) * (1.0f / D);
  float rstd = rsqrtf(var + 1e-5f);
  float2 gv = *(const float2*)(g + lane * 2);
  float2 bv = *(const float2*)(b + lane * 2);
  float o0 = d0 * rstd * gv.x + bv.x;
  float o1 = d1 * rstd * gv.y + bv.y;
  unsigned int p = (unsigned int)bf16r(o0) | ((unsigned int)bf16r(o1) << 16);
  *(unsigned int*)(xnq + (size_t)w * D + lane * 2) = p;
}

// K2: weight prep — bf16 transposed copies + we = W_edge @ att_edge
__global__ void k_prep(const float* __restrict__ W_lin, const float* __restrict__ W1,
                       const float* __restrict__ W2, const float* __restrict__ W_edge,
                       const float* __restrict__ att_edge,
                       unsigned short* __restrict__ Wlt, unsigned short* __restrict__ W1t,
                       unsigned short* __restrict__ W2t, float* __restrict__ we){
  int t = blockIdx.x * blockDim.x + threadIdx.x;
  if (t < 128 * 128){
    int c = t >> 7, k = t & 127;
    Wlt[t] = bf16r(W_lin[k * 128 + c]);
  } else if (t < 128 * 128 + 512 * 128){
    int u = t - 128 * 128; int c = u >> 7, k = u & 127;
    W1t[u] = bf16r(W1[k * 512 + c]);
  } else if (t < 128 * 128 + 512 * 128 + 128 * 512){
    int u = t - (128 * 128 + 512 * 128); int c = u >> 9, k = u & 511;
    W2t[u] = bf16r(W2[k * 128 + c]);
  } else {
    int u = t - (128 * 128 + 512 * 128 + 128 * 512);
    if (u < 128){
      float s = 0.f;
      for (int j = 0; j < 128; ++j) s += W_edge[u * 128 + j] * att_edge[j];
      we[u] = s;
    }
  }
}

// K3: h = xn @ W_lin  (bf16 MFMA, f32 out). 4 waves/block, 64 rows/block.
__global__ __launch_bounds__(256) void k_hgemm(const unsigned short* __restrict__ xnq,
                                               const unsigned short* __restrict__ Wlt,
                                               float* __restrict__ h, int N){
  int wid = threadIdx.x >> 6, lane = threadIdx.x & 63;
  int rb = blockIdx.x * 64 + wid * 16;
  int row = rb + (lane & 15);
  int rowc = row < N ? row : N - 1;
  int ksub = (lane >> 4) * 8;
  short8 a[4];
#pragma unroll
  for (int kb = 0; kb < 4; ++kb)
    a[kb] = *(const short8*)(xnq + (size_t)rowc * 128 + kb * 32 + ksub);
  int r0 = rb + (lane >> 4) * 4;
#pragma unroll
  for (int ct = 0; ct < 8; ++ct){
    int col = ct * 16 + (lane & 15);
    f32x4 acc = {0.f, 0.f, 0.f, 0.f};
#pragma unroll
    for (int kb = 0; kb < 4; ++kb){
      short8 bf = *(const short8*)(Wlt + (size_t)col * 128 + kb * 32 + ksub);
      acc = __builtin_amdgcn_mfma_f32_16x16x32_bf16(a[kb], bf, acc, 0, 0, 0);
    }
#pragma unroll
    for (int j = 0; j < 4; ++j){
      int r = r0 + j;
      if (r < N) h[(size_t)r * 128 + col] = acc[j];
    }
  }
}

// K4: a_src[n] = h[n].att_src ; a_dst[n] = h[n].att_dst  (wave per row)
__global__ void k_attdots(const float* __restrict__ h, const float* __restrict__ att_src,
                          const float* __restrict__ att_dst, float* __restrict__ asrc,
                          float* __restrict__ adst, int N){
  int w = (blockIdx.x * blockDim.x + threadIdx.x) >> 6;
  int lane = threadIdx.x & 63;
  if (w >= N) return;
  float2 hv = *(const float2*)(h + (size_t)w * 128 + lane * 2);
  float2 s2 = *(const float2*)(att_src + lane * 2);
  float2 d2 = *(const float2*)(att_dst + lane * 2);
  float s = wred_sum(hv.x * s2.x + hv.y * s2.y);
  float d = wred_sum(hv.x * d2.x + hv.y * d2.y);
  if (lane == 0){ asrc[w] = s; adst[w] = d; }
}

// K5: per-edge logits (2 edges per wave), count degree
__global__ void k_edge(const float* __restrict__ ea, const int* __restrict__ ei,
                       const float* __restrict__ we, const float* __restrict__ asrc,
                       const float* __restrict__ adst, float* __restrict__ alpha,
                       int* __restrict__ cnt, int E){
  int gw = (blockIdx.x * blockDim.x + threadIdx.x) >> 6;
  int lane = threadIdx.x & 63;
  int e = gw * 2 + (lane >> 5);
  int li = lane & 31;
  if (e >= E) return;
  float4 v = *(const float4*)(ea + (size_t)e * 128 + li * 4);
  float4 w = *(const float4*)(we + li * 4);
  float s = v.x * w.x + v.y * w.y + v.z * w.z + v.w * w.w;
#pragma unroll
  for (int m = 16; m; m >>= 1) s += __shfl_xor(s, m);
  if (li == 0){
    int sn = ei[e], dn = ei[E + e];
    float al = asrc[sn] + adst[dn] + s;
    al = al > 0.f ? al : NEG_SLOPE * al;
    alpha[e] = al;
    atomicAdd(&cnt[dn], 1);
  }
}

// K6: exclusive scan of cnt -> start[0..N] (single block, chunked)
__global__ void k_scan(const int* __restrict__ cnt, int* __restrict__ start, int N){
  __shared__ int sd[1024];
  int t = threadIdx.x;
  int chunk = (N + 1023) / 1024;
  int lo = t * chunk;
  int hi = lo + chunk; if (hi > N) hi = N;
  int s = 0;
  for (int i = lo; i < hi; ++i) s += cnt[i];
  sd[t] = s;
  __syncthreads();
  for (int off = 1; off < 1024; off <<= 1){
    int v = (t >= off) ? sd[t - off] : 0;
    __syncthreads();
    sd[t] += v;
    __syncthreads();
  }
  int run = sd[t] - s;
  for (int i = lo; i < hi; ++i){ start[i] = run; run += cnt[i]; }
  if (t == 1023) start[N] = sd[1023];
}

// K7: bucket edges by dst (CSR), carrying src and alpha
__global__ void k_scatter(const int* __restrict__ ei, const float* __restrict__ alpha,
                          const int* __restrict__ start, int* __restrict__ cursor,
                          int* __restrict__ esrc_s, float* __restrict__ ealpha_s, int E){
  int e = blockIdx.x * blockDim.x + threadIdx.x;
  if (e >= E) return;
  int dn = ei[E + e];
  int pos = atomicAdd(&cursor[dn], 1);
  int slot = start[dn] + pos;
  esrc_s[slot] = ei[e];
  ealpha_s[slot] = alpha[e];
}

// K8: per-node softmax + weighted gather of h[src] + residual + LN2 -> out(x1), xn2q(bf16)
__global__ void k_agg(const float* __restrict__ x, const float* __restrict__ h,
                      const int* __restrict__ start, const int* __restrict__ esrc_s,
                      const float* __restrict__ ealpha_s, const float* __restrict__ gat_bias,
                      const float* __restrict__ g2, const float* __restrict__ b2,
                      float* __restrict__ out, unsigned short* __restrict__ xn2q, int N){
  int n = (blockIdx.x * blockDim.x + threadIdx.x) >> 6;
  int lane = threadIdx.x & 63;
  if (n >= N) return;
  int beg = start[n], end = start[n + 1];
  float m = -1e30f;
  for (int i = beg + lane; i < end; i += 64) m = fmaxf(m, ealpha_s[i]);
  m = wred_max(m);
  float ds = 0.f;
  for (int i = beg + lane; i < end; i += 64) ds += __expf(ealpha_s[i] - m);
  ds = wred_sum(ds);
  float inv = (end > beg) ? 1.f / fmaxf(ds, 1e-16f) : 0.f;
  float a0 = 0.f, a1 = 0.f;
  for (int s = beg; s < end; ++s){
    float c = __expf(ealpha_s[s] - m) * inv;
    int sn = esrc_s[s];
    float2 hv = *(const float2*)(h + (size_t)sn * 128 + lane * 2);
    a0 += c * hv.x; a1 += c * hv.y;
  }
  float2 xv  = *(const float2*)(x + (size_t)n * 128 + lane * 2);
  float2 gbv = *(const float2*)(gat_bias + lane * 2);
  float r0 = xv.x + a0 + gbv.x;
  float r1 = xv.y + a1 + gbv.y;
  float mu = wred_sum(r0 + r1) * (1.0f / 128.f);
  float d0 = r0 - mu, d1 = r1 - mu;
  float var = wred_sum(d0 * d0 + d1 * d1) * (1.0f / 128.f);
  float rstd = rsqrtf(var + 1e-5f);
  float2 gv = *(const float2*)(g2 + lane * 2);
  float2 bv = *(const float2*)(b2 + lane * 2);
  float o0 = d0 * rstd * gv.x + bv.x;
  float o1 = d1 * rstd * gv.y + bv.y;
  *(float2*)(out + (size_t)n * 128 + lane * 2) = make_float2(r0, r1);
  unsigned int p = (unsigned int)bf16r(o0) | ((unsigned int)bf16r(o1) << 16);
  *(unsigned int*)(xn2q + (size_t)n * 128 + lane * 2) = p;
}

// K9: fused FFN — hidden (64x512) lives only in swizzled LDS; out += relu(xn2@W1+b1)@W2+b2
__global__ __launch_bounds__(256) void k_ffn(const unsigned short* __restrict__ xn2q,
                                             const unsigned short* __restrict__ W1t,
                                             const unsigned short* __restrict__ W2t,
                                             const float* __restrict__ b1,
                                             const float* __restrict__ b2,
                                             float* __restrict__ out, int N){
  __shared__ unsigned short hid[64 * 512];  // 64 KiB, XOR-swizzled rows (1024B stride)
  int wid = threadIdx.x >> 6, lane = threadIdx.x & 63;
  int rb = blockIdx.x * 64;
  int wr = rb + wid * 16;
  int arow = wr + (lane & 15);
  int arowc = arow < N ? arow : N - 1;
  int ksub = (lane >> 4) * 8;
  short8 a[4];
#pragma unroll
  for (int kb = 0; kb < 4; ++kb)
    a[kb] = *(const short8*)(xn2q + (size_t)arowc * 128 + kb * 32 + ksub);
  int lr0 = wid * 16 + (lane >> 4) * 4;
#pragma unroll 4
  for (int ct = 0; ct < 32; ++ct){
    int col = ct * 16 + (lane & 15);
    f32x4 acc = {0.f, 0.f, 0.f, 0.f};
#pragma unroll
    for (int kb = 0; kb < 4; ++kb){
      short8 bf = *(const short8*)(W1t + (size_t)col * 128 + kb * 32 + ksub);
      acc = __builtin_amdgcn_mfma_f32_16x16x32_bf16(a[kb], bf, acc, 0, 0, 0);
    }
    float bias = b1[col];
#pragma unroll
    for (int j = 0; j < 4; ++j){
      float v = acc[j] + bias;
      v = v > 0.f ? v : 0.f;
      int row = lr0 + j;
      int byte = (col * 2) ^ ((row & 7) << 4);
      *(unsigned short*)((char*)hid + row * 1024 + byte) = bf16r(v);
    }
  }
  __syncthreads();
  f32x4 acc2[8];
#pragma unroll
  for (int ct = 0; ct < 8; ++ct) acc2[ct] = (f32x4){0.f, 0.f, 0.f, 0.f};
  int arow2 = wid * 16 + (lane & 15);
#pragma unroll 2
  for (int kb = 0; kb < 16; ++kb){
    int kbyte = (kb * 32 + ksub) * 2;
    int sb = kbyte ^ ((arow2 & 7) << 4);
    short8 af = *(const short8*)((const char*)hid + arow2 * 1024 + sb);
#pragma unroll
    for (int ct = 0; ct < 8; ++ct){
      int col = ct * 16 + (lane & 15);
      short8 bf = *(const short8*)(W2t + (size_t)col * 512 + kb * 32 + ksub);
      acc2[ct] = __builtin_amdgcn_mfma_f32_16x16x32_bf16(af, bf, acc2[ct], 0, 0, 0);
    }
  }
  int r0 = wr + (lane >> 4) * 4;
#pragma unroll
  for (int ct = 0; ct < 8; ++ct){
    int col = ct * 16 + (lane & 15);
    float bias = b2[col];
#pragma unroll
    for (int j = 0; j < 4; ++j){
      int row = r0 + j;
      if (row < N) out[(size_t)row * 128 + col] += acc2[ct][j] + bias;
    }
  }
}

extern "C" void kernel_launch(void* const* d_in, const int* in_sizes, int n_in,
                              void* d_out, int out_size, void* d_ws, size_t ws_size,
                              hipStream_t stream){
  const float* x        = (const float*)d_in[0];
  const int*   ei       = (const int*)  d_in[1];
  const float* ea       = (const float*)d_in[2];
  const float* ln1_g    = (const float*)d_in[3];
  const float* ln1_b    = (const float*)d_in[4];
  const float* W_lin    = (const float*)d_in[5];
  const float* att_src  = (const float*)d_in[6];
  const float* att_dst  = (const float*)d_in[7];
  const float* W_edge   = (const float*)d_in[8];
  const float* att_edge = (const float*)d_in[9];
  const float* gat_bias = (const float*)d_in[10];
  const float* ln2_g    = (const float*)d_in[11];
  const float* ln2_b    = (const float*)d_in[12];
  const float* W1       = (const float*)d_in[13];
  const float* b1       = (const float*)d_in[14];
  const float* W2       = (const float*)d_in[15];
  const float* b2       = (const float*)d_in[16];

  const int N = in_sizes[0] / 128;
  const int E = in_sizes[2] / 128;
  float* out = (float*)d_out;

  char* p = (char*)d_ws;
  auto carve = [&](size_t bytes) -> char* {
    char* r = p; p += (bytes + 255) & ~(size_t)255; return r;
  };
  unsigned short* xnq      = (unsigned short*)carve((size_t)N * 128 * 2); // reused as xn2q
  float*          h        = (float*)carve((size_t)N * 128 * 4);
  float*          asrc     = (float*)carve((size_t)N * 4);
  float*          adst     = (float*)carve((size_t)N * 4);
  float*          alpha    = (float*)carve((size_t)E * 4);
  float*          ealpha_s = (float*)carve((size_t)E * 4);
  int*            esrc_s   = (int*)carve((size_t)E * 4);
  int*            cnt      = (int*)carve((size_t)N * 4);
  int*            cursor   = (int*)carve((size_t)N * 4);
  int*            start    = (int*)carve((size_t)(N + 1) * 4);
  unsigned short* Wlt      = (unsigned short*)carve(128 * 128 * 2);
  unsigned short* W1t      = (unsigned short*)carve(512 * 128 * 2);
  unsigned short* W2t      = (unsigned short*)carve(128 * 512 * 2);
  float*          we       = (float*)carve(128 * 4);
  unsigned short* xn2q     = xnq;  // alias: xnq dead after k_hgemm

  hipMemsetAsync(cnt, 0, (size_t)N * 4, stream);
  hipMemsetAsync(cursor, 0, (size_t)N * 4, stream);

  int nwb = (N + 3) / 4;  // 4 rows per 256-thread block (wave per row)
  k_ln1<<<nwb, 256, 0, stream>>>(x, ln1_g, ln1_b, xnq, N);
  k_prep<<<(128*128 + 512*128 + 128*512 + 128 + 255) / 256, 256, 0, stream>>>(
      W_lin, W1, W2, W_edge, att_edge, Wlt, W1t, W2t, we);
  k_hgemm<<<(N + 63) / 64, 256, 0, stream>>>(xnq, Wlt, h, N);
  k_attdots<<<nwb, 256, 0, stream>>>(h, att_src, att_dst, asrc, adst, N);
  k_edge<<<(E + 7) / 8, 256, 0, stream>>>(ea, ei, we, asrc, adst, alpha, cnt, E);
  k_scan<<<1, 1024, 0, stream>>>(cnt, start, N);
  k_scatter<<<(E + 255) / 256, 256, 0, stream>>>(ei, alpha, start, cursor, esrc_s, ealpha_s, E);
  k_agg<<<nwb, 256, 0, stream>>>(x, h, start, esrc_s, ealpha_s, gat_bias, ln2_g, ln2_b,
                                 out, xn2q, N);
  k_ffn<<<(N + 63) / 64, 256, 0, stream>>>(xn2q, W1t, W2t, b1, b2, out, N);
}

// Round 2
// 472.982 us; speedup vs baseline: 1.0411x; 1.0411x over previous
//
#include <hip/hip_runtime.h>

#define D 128
#define NEG_SLOPE 0.2f

typedef __attribute__((ext_vector_type(8))) short short8;
typedef __attribute__((ext_vector_type(4))) float f32x4;

__device__ __forceinline__ float wred_sum(float v){
#pragma unroll
  for (int m = 32; m; m >>= 1) v += __shfl_xor(v, m);
  return v;
}
__device__ __forceinline__ float wred_max(float v){
#pragma unroll
  for (int m = 32; m; m >>= 1) v = fmaxf(v, __shfl_xor(v, m));
  return v;
}
__device__ __forceinline__ unsigned short bf16r(float f){
  unsigned int u = __float_as_uint(f);
  u += 0x7fffu + ((u >> 16) & 1u);
  return (unsigned short)(u >> 16);
}
__device__ __forceinline__ float bf2f(unsigned int hi16){
  return __uint_as_float(hi16 << 16);
}

// K1: xn = LN(x, ln1) -> bf16 (wave/row); also zeroes cnt+cursor (replaces memsets)
__global__ void k_ln1(const float* __restrict__ x, const float* __restrict__ g,
                      const float* __restrict__ b, unsigned short* __restrict__ xnq,
                      int* __restrict__ cnt, int* __restrict__ cursor, int N){
  int gid = blockIdx.x * blockDim.x + threadIdx.x;
  if (gid < N){ cnt[gid] = 0; cursor[gid] = 0; }
  int w = gid >> 6;
  int lane = threadIdx.x & 63;
  if (w >= N) return;
  float2 v = *(const float2*)(x + (size_t)w * D + lane * 2);
  float mu = wred_sum(v.x + v.y) * (1.0f / D);
  float d0 = v.x - mu, d1 = v.y - mu;
  float var = wred_sum(d0 * d0 + d1 * d1) * (1.0f / D);
  float rstd = rsqrtf(var + 1e-5f);
  float2 gv = *(const float2*)(g + lane * 2);
  float2 bv = *(const float2*)(b + lane * 2);
  float o0 = d0 * rstd * gv.x + bv.x;
  float o1 = d1 * rstd * gv.y + bv.y;
  unsigned int p = (unsigned int)bf16r(o0) | ((unsigned int)bf16r(o1) << 16);
  *(unsigned int*)(xnq + (size_t)w * D + lane * 2) = p;
}

// K2: weight prep — bf16 transposed copies + we = W_edge @ att_edge
__global__ void k_prep(const float* __restrict__ W_lin, const float* __restrict__ W1,
                       const float* __restrict__ W2, const float* __restrict__ W_edge,
                       const float* __restrict__ att_edge,
                       unsigned short* __restrict__ Wlt, unsigned short* __restrict__ W1t,
                       unsigned short* __restrict__ W2t, float* __restrict__ we){
  int t = blockIdx.x * blockDim.x + threadIdx.x;
  if (t < 128 * 128){
    int c = t >> 7, k = t & 127;
    Wlt[t] = bf16r(W_lin[k * 128 + c]);
  } else if (t < 128 * 128 + 512 * 128){
    int u = t - 128 * 128; int c = u >> 7, k = u & 127;
    W1t[u] = bf16r(W1[k * 512 + c]);
  } else if (t < 128 * 128 + 512 * 128 + 128 * 512){
    int u = t - (128 * 128 + 512 * 128); int c = u >> 9, k = u & 511;
    W2t[u] = bf16r(W2[k * 128 + c]);
  } else {
    int u = t - (128 * 128 + 512 * 128 + 128 * 512);
    if (u < 128){
      float s = 0.f;
      for (int j = 0; j < 128; ++j) s += W_edge[u * 128 + j] * att_edge[j];
      we[u] = s;
    }
  }
}

// K3: h = xn @ W_lin (bf16 MFMA) -> hq (bf16), fused a_src/a_dst dots from f32 acc.
__global__ __launch_bounds__(256) void k_hgemm(const unsigned short* __restrict__ xnq,
                                               const unsigned short* __restrict__ Wlt,
                                               const float* __restrict__ att_src,
                                               const float* __restrict__ att_dst,
                                               unsigned short* __restrict__ hq,
                                               float* __restrict__ asrc,
                                               float* __restrict__ adst, int N){
  int wid = threadIdx.x >> 6, lane = threadIdx.x & 63;
  int rb = blockIdx.x * 64 + wid * 16;
  int row = rb + (lane & 15);
  int rowc = row < N ? row : N - 1;
  int ksub = (lane >> 4) * 8;
  short8 a[4];
#pragma unroll
  for (int kb = 0; kb < 4; ++kb)
    a[kb] = *(const short8*)(xnq + (size_t)rowc * 128 + kb * 32 + ksub);
  f32x4 acc[8];
#pragma unroll
  for (int ct = 0; ct < 8; ++ct) acc[ct] = (f32x4){0.f, 0.f, 0.f, 0.f};
#pragma unroll
  for (int ct = 0; ct < 8; ++ct){
    int col = ct * 16 + (lane & 15);
#pragma unroll
    for (int kb = 0; kb < 4; ++kb){
      short8 bf = *(const short8*)(Wlt + (size_t)col * 128 + kb * 32 + ksub);
      acc[ct] = __builtin_amdgcn_mfma_f32_16x16x32_bf16(a[kb], bf, acc[ct], 0, 0, 0);
    }
  }
  int r0 = rb + (lane >> 4) * 4;
  // write hq (bf16)
#pragma unroll
  for (int ct = 0; ct < 8; ++ct){
    int col = ct * 16 + (lane & 15);
#pragma unroll
    for (int j = 0; j < 4; ++j){
      int r = r0 + j;
      if (r < N) hq[(size_t)r * 128 + col] = bf16r(acc[ct][j]);
    }
  }
  // fused attention dots: per row, sum over 128 cols (8 ct * 16 lanes)
  float as_v[8], ad_v[8];
#pragma unroll
  for (int ct = 0; ct < 8; ++ct){
    int col = ct * 16 + (lane & 15);
    as_v[ct] = att_src[col];
    ad_v[ct] = att_dst[col];
  }
  float ps[4] = {0.f, 0.f, 0.f, 0.f}, pd[4] = {0.f, 0.f, 0.f, 0.f};
#pragma unroll
  for (int ct = 0; ct < 8; ++ct)
#pragma unroll
    for (int j = 0; j < 4; ++j){
      ps[j] += acc[ct][j] * as_v[ct];
      pd[j] += acc[ct][j] * ad_v[ct];
    }
#pragma unroll
  for (int m = 1; m < 16; m <<= 1)
#pragma unroll
    for (int j = 0; j < 4; ++j){
      ps[j] += __shfl_xor(ps[j], m);
      pd[j] += __shfl_xor(pd[j], m);
    }
  if ((lane & 15) == 0){
#pragma unroll
    for (int j = 0; j < 4; ++j){
      int r = r0 + j;
      if (r < N){ asrc[r] = ps[j]; adst[r] = pd[j]; }
    }
  }
}

// K5: per-edge logits (2 edges per wave), count degree
__global__ void k_edge(const float* __restrict__ ea, const int* __restrict__ ei,
                       const float* __restrict__ we, const float* __restrict__ asrc,
                       const float* __restrict__ adst, float* __restrict__ alpha,
                       int* __restrict__ cnt, int E){
  int gw = (blockIdx.x * blockDim.x + threadIdx.x) >> 6;
  int lane = threadIdx.x & 63;
  int e = gw * 2 + (lane >> 5);
  int li = lane & 31;
  if (e >= E) return;
  float4 v = *(const float4*)(ea + (size_t)e * 128 + li * 4);
  float4 w = *(const float4*)(we + li * 4);
  float s = v.x * w.x + v.y * w.y + v.z * w.z + v.w * w.w;
#pragma unroll
  for (int m = 16; m; m >>= 1) s += __shfl_xor(s, m);
  if (li == 0){
    int sn = ei[e], dn = ei[E + e];
    float al = asrc[sn] + adst[dn] + s;
    al = al > 0.f ? al : NEG_SLOPE * al;
    alpha[e] = al;
    atomicAdd(&cnt[dn], 1);
  }
}

// K6: exclusive scan of cnt -> start[0..N] (single block, chunked)
__global__ void k_scan(const int* __restrict__ cnt, int* __restrict__ start, int N){
  __shared__ int sd[1024];
  int t = threadIdx.x;
  int chunk = (N + 1023) / 1024;
  int lo = t * chunk;
  int hi = lo + chunk; if (hi > N) hi = N;
  int s = 0;
  for (int i = lo; i < hi; ++i) s += cnt[i];
  sd[t] = s;
  __syncthreads();
  for (int off = 1; off < 1024; off <<= 1){
    int v = (t >= off) ? sd[t - off] : 0;
    __syncthreads();
    sd[t] += v;
    __syncthreads();
  }
  int run = sd[t] - s;
  for (int i = lo; i < hi; ++i){ start[i] = run; run += cnt[i]; }
  if (t == 1023) start[N] = sd[1023];
}

// K7: bucket edges by dst (CSR), carrying src and alpha
__global__ void k_scatter(const int* __restrict__ ei, const float* __restrict__ alpha,
                          const int* __restrict__ start, int* __restrict__ cursor,
                          int* __restrict__ esrc_s, float* __restrict__ ealpha_s, int E){
  int e = blockIdx.x * blockDim.x + threadIdx.x;
  if (e >= E) return;
  int dn = ei[E + e];
  int pos = atomicAdd(&cursor[dn], 1);
  int slot = start[dn] + pos;
  esrc_s[slot] = ei[e];
  ealpha_s[slot] = alpha[e];
}

// K8: per-node softmax + weighted gather of hq[src] + residual + LN2 -> out, xn2q(bf16)
__global__ void k_agg(const float* __restrict__ x, const unsigned short* __restrict__ hq,
                      const int* __restrict__ start, const int* __restrict__ esrc_s,
                      const float* __restrict__ ealpha_s, const float* __restrict__ gat_bias,
                      const float* __restrict__ g2, const float* __restrict__ b2,
                      float* __restrict__ out, unsigned short* __restrict__ xn2q, int N){
  int n = (blockIdx.x * blockDim.x + threadIdx.x) >> 6;
  int lane = threadIdx.x & 63;
  if (n >= N) return;
  int beg = start[n], end = start[n + 1];
  float m = -1e30f;
  for (int i = beg + lane; i < end; i += 64) m = fmaxf(m, ealpha_s[i]);
  m = wred_max(m);
  float ds = 0.f;
  for (int i = beg + lane; i < end; i += 64) ds += __expf(ealpha_s[i] - m);
  ds = wred_sum(ds);
  float inv = (end > beg) ? 1.f / fmaxf(ds, 1e-16f) : 0.f;
  float a0 = 0.f, a1 = 0.f;
  for (int s = beg; s < end; ++s){
    float c = __expf(ealpha_s[s] - m) * inv;
    int sn = esrc_s[s];
    unsigned int hv = *(const unsigned int*)(hq + (size_t)sn * 128 + lane * 2);
    a0 += c * bf2f(hv & 0xffffu);
    a1 += c * bf2f(hv >> 16);
  }
  float2 xv  = *(const float2*)(x + (size_t)n * 128 + lane * 2);
  float2 gbv = *(const float2*)(gat_bias + lane * 2);
  float r0 = xv.x + a0 + gbv.x;
  float r1 = xv.y + a1 + gbv.y;
  float mu = wred_sum(r0 + r1) * (1.0f / 128.f);
  float d0 = r0 - mu, d1 = r1 - mu;
  float var = wred_sum(d0 * d0 + d1 * d1) * (1.0f / 128.f);
  float rstd = rsqrtf(var + 1e-5f);
  float2 gv = *(const float2*)(g2 + lane * 2);
  float2 bv = *(const float2*)(b2 + lane * 2);
  float o0 = d0 * rstd * gv.x + bv.x;
  float o1 = d1 * rstd * gv.y + bv.y;
  *(float2*)(out + (size_t)n * 128 + lane * 2) = make_float2(r0, r1);
  unsigned int p = (unsigned int)bf16r(o0) | ((unsigned int)bf16r(o1) << 16);
  *(unsigned int*)(xn2q + (size_t)n * 128 + lane * 2) = p;
}

// K9: fused FFN — hidden (64x512) lives only in swizzled LDS; out += relu(xn2@W1+b1)@W2+b2
__global__ __launch_bounds__(256) void k_ffn(const unsigned short* __restrict__ xn2q,
                                             const unsigned short* __restrict__ W1t,
                                             const unsigned short* __restrict__ W2t,
                                             const float* __restrict__ b1,
                                             const float* __restrict__ b2,
                                             float* __restrict__ out, int N){
  __shared__ unsigned short hid[64 * 512];  // 64 KiB, XOR-swizzled rows (1024B stride)
  int wid = threadIdx.x >> 6, lane = threadIdx.x & 63;
  int rb = blockIdx.x * 64;
  int wr = rb + wid * 16;
  int arow = wr + (lane & 15);
  int arowc = arow < N ? arow : N - 1;
  int ksub = (lane >> 4) * 8;
  short8 a[4];
#pragma unroll
  for (int kb = 0; kb < 4; ++kb)
    a[kb] = *(const short8*)(xn2q + (size_t)arowc * 128 + kb * 32 + ksub);
  int lr0 = wid * 16 + (lane >> 4) * 4;
#pragma unroll 4
  for (int ct = 0; ct < 32; ++ct){
    int col = ct * 16 + (lane & 15);
    f32x4 acc = {0.f, 0.f, 0.f, 0.f};
#pragma unroll
    for (int kb = 0; kb < 4; ++kb){
      short8 bf = *(const short8*)(W1t + (size_t)col * 128 + kb * 32 + ksub);
      acc = __builtin_amdgcn_mfma_f32_16x16x32_bf16(a[kb], bf, acc, 0, 0, 0);
    }
    float bias = b1[col];
#pragma unroll
    for (int j = 0; j < 4; ++j){
      float v = acc[j] + bias;
      v = v > 0.f ? v : 0.f;
      int row = lr0 + j;
      int byte = (col * 2) ^ ((row & 7) << 4);
      *(unsigned short*)((char*)hid + row * 1024 + byte) = bf16r(v);
    }
  }
  __syncthreads();
  f32x4 acc2[8];
#pragma unroll
  for (int ct = 0; ct < 8; ++ct) acc2[ct] = (f32x4){0.f, 0.f, 0.f, 0.f};
  int arow2 = wid * 16 + (lane & 15);
#pragma unroll 2
  for (int kb = 0; kb < 16; ++kb){
    int kbyte = (kb * 32 + ksub) * 2;
    int sb = kbyte ^ ((arow2 & 7) << 4);
    short8 af = *(const short8*)((const char*)hid + arow2 * 1024 + sb);
#pragma unroll
    for (int ct = 0; ct < 8; ++ct){
      int col = ct * 16 + (lane & 15);
      short8 bf = *(const short8*)(W2t + (size_t)col * 512 + kb * 32 + ksub);
      acc2[ct] = __builtin_amdgcn_mfma_f32_16x16x32_bf16(af, bf, acc2[ct], 0, 0, 0);
    }
  }
  int r0 = wr + (lane >> 4) * 4;
#pragma unroll
  for (int ct = 0; ct < 8; ++ct){
    int col = ct * 16 + (lane & 15);
    float bias = b2[col];
#pragma unroll
    for (int j = 0; j < 4; ++j){
      int row = r0 + j;
      if (row < N) out[(size_t)row * 128 + col] += acc2[ct][j] + bias;
    }
  }
}

extern "C" void kernel_launch(void* const* d_in, const int* in_sizes, int n_in,
                              void* d_out, int out_size, void* d_ws, size_t ws_size,
                              hipStream_t stream){
  const float* x        = (const float*)d_in[0];
  const int*   ei       = (const int*)  d_in[1];
  const float* ea       = (const float*)d_in[2];
  const float* ln1_g    = (const float*)d_in[3];
  const float* ln1_b    = (const float*)d_in[4];
  const float* W_lin    = (const float*)d_in[5];
  const float* att_src  = (const float*)d_in[6];
  const float* att_dst  = (const float*)d_in[7];
  const float* W_edge   = (const float*)d_in[8];
  const float* att_edge = (const float*)d_in[9];
  const float* gat_bias = (const float*)d_in[10];
  const float* ln2_g    = (const float*)d_in[11];
  const float* ln2_b    = (const float*)d_in[12];
  const float* W1       = (const float*)d_in[13];
  const float* b1       = (const float*)d_in[14];
  const float* W2       = (const float*)d_in[15];
  const float* b2       = (const float*)d_in[16];

  const int N = in_sizes[0] / 128;
  const int E = in_sizes[2] / 128;
  float* out = (float*)d_out;

  char* p = (char*)d_ws;
  auto carve = [&](size_t bytes) -> char* {
    char* r = p; p += (bytes + 255) & ~(size_t)255; return r;
  };
  unsigned short* xnq      = (unsigned short*)carve((size_t)N * 128 * 2); // reused as xn2q
  unsigned short* hq       = (unsigned short*)carve((size_t)N * 128 * 2);
  float*          asrc     = (float*)carve((size_t)N * 4);
  float*          adst     = (float*)carve((size_t)N * 4);
  float*          alpha    = (float*)carve((size_t)E * 4);
  float*          ealpha_s = (float*)carve((size_t)E * 4);
  int*            esrc_s   = (int*)carve((size_t)E * 4);
  int*            cnt      = (int*)carve((size_t)N * 4);
  int*            cursor   = (int*)carve((size_t)N * 4);
  int*            start    = (int*)carve((size_t)(N + 1) * 4);
  unsigned short* Wlt      = (unsigned short*)carve(128 * 128 * 2);
  unsigned short* W1t      = (unsigned short*)carve(512 * 128 * 2);
  unsigned short* W2t      = (unsigned short*)carve(128 * 512 * 2);
  float*          we       = (float*)carve(128 * 4);
  unsigned short* xn2q     = xnq;  // alias: xnq dead after k_hgemm

  int nwb = (N + 3) / 4;  // 4 rows per 256-thread block (wave per row)
  k_ln1<<<nwb, 256, 0, stream>>>(x, ln1_g, ln1_b, xnq, cnt, cursor, N);
  k_prep<<<(128*128 + 512*128 + 128*512 + 128 + 255) / 256, 256, 0, stream>>>(
      W_lin, W1, W2, W_edge, att_edge, Wlt, W1t, W2t, we);
  k_hgemm<<<(N + 63) / 64, 256, 0, stream>>>(xnq, Wlt, att_src, att_dst, hq, asrc, adst, N);
  k_edge<<<(E + 7) / 8, 256, 0, stream>>>(ea, ei, we, asrc, adst, alpha, cnt, E);
  k_scan<<<1, 1024, 0, stream>>>(cnt, start, N);
  k_scatter<<<(E + 255) / 256, 256, 0, stream>>>(ei, alpha, start, cursor, esrc_s, ealpha_s, E);
  k_agg<<<nwb, 256, 0, stream>>>(x, hq, start, esrc_s, ealpha_s, gat_bias, ln2_g, ln2_b,
                                 out, xn2q, N);
  k_ffn<<<(N + 63) / 64, 256, 0, stream>>>(xn2q, W1t, W2t, b1, b2, out, N);
}

// Round 3
// 438.205 us; speedup vs baseline: 1.1237x; 1.0794x over previous
//
#include <hip/hip_runtime.h>

#define D 128
#define NEG_SLOPE 0.2f

typedef __attribute__((ext_vector_type(8))) short short8;
typedef __attribute__((ext_vector_type(4))) float f32x4;

__device__ __forceinline__ float wred_sum(float v){
#pragma unroll
  for (int m = 32; m; m >>= 1) v += __shfl_xor(v, m);
  return v;
}
__device__ __forceinline__ float wred_max(float v){
#pragma unroll
  for (int m = 32; m; m >>= 1) v = fmaxf(v, __shfl_xor(v, m));
  return v;
}
__device__ __forceinline__ unsigned short bf16r(float f){
  unsigned int u = __float_as_uint(f);
  u += 0x7fffu + ((u >> 16) & 1u);
  return (unsigned short)(u >> 16);
}
__device__ __forceinline__ float bf2f(unsigned int hi16){
  return __uint_as_float(hi16 << 16);
}

// K1: xn = LN(x, ln1) -> bf16 (wave/row)
__global__ void k_ln1(const float* __restrict__ x, const float* __restrict__ g,
                      const float* __restrict__ b, unsigned short* __restrict__ xnq, int N){
  int w = (blockIdx.x * blockDim.x + threadIdx.x) >> 6;
  int lane = threadIdx.x & 63;
  if (w >= N) return;
  float2 v = *(const float2*)(x + (size_t)w * D + lane * 2);
  float mu = wred_sum(v.x + v.y) * (1.0f / D);
  float d0 = v.x - mu, d1 = v.y - mu;
  float var = wred_sum(d0 * d0 + d1 * d1) * (1.0f / D);
  float rstd = rsqrtf(var + 1e-5f);
  float2 gv = *(const float2*)(g + lane * 2);
  float2 bv = *(const float2*)(b + lane * 2);
  float o0 = d0 * rstd * gv.x + bv.x;
  float o1 = d1 * rstd * gv.y + bv.y;
  unsigned int p = (unsigned int)bf16r(o0) | ((unsigned int)bf16r(o1) << 16);
  *(unsigned int*)(xnq + (size_t)w * D + lane * 2) = p;
}

// K2: weight prep (bf16 transposed copies + we = W_edge @ att_edge) + zero cnt/cursor
__global__ void k_prep(const float* __restrict__ W_lin, const float* __restrict__ W1,
                       const float* __restrict__ W2, const float* __restrict__ W_edge,
                       const float* __restrict__ att_edge,
                       unsigned short* __restrict__ Wlt, unsigned short* __restrict__ W1t,
                       unsigned short* __restrict__ W2t, float* __restrict__ we,
                       int* __restrict__ cnt, int* __restrict__ cursor, int N){
  int t = blockIdx.x * blockDim.x + threadIdx.x;
  if (t < N) cnt[t] = 0;
  else if (t < 2 * N) cursor[t - N] = 0;
  if (t < 128 * 128){
    int c = t >> 7, k = t & 127;
    Wlt[t] = bf16r(W_lin[k * 128 + c]);
  } else if (t < 128 * 128 + 512 * 128){
    int u = t - 128 * 128; int c = u >> 7, k = u & 127;
    W1t[u] = bf16r(W1[k * 512 + c]);
  } else if (t < 128 * 128 + 512 * 128 + 128 * 512){
    int u = t - (128 * 128 + 512 * 128); int c = u >> 9, k = u & 511;
    W2t[u] = bf16r(W2[k * 128 + c]);
  } else {
    int u = t - (128 * 128 + 512 * 128 + 128 * 512);
    if (u < 128){
      float s = 0.f;
      for (int j = 0; j < 128; ++j) s += W_edge[u * 128 + j] * att_edge[j];
      we[u] = s;
    }
  }
}

// K3: degree count (thread/edge)
__global__ void k_count(const int* __restrict__ ei, int* __restrict__ cnt, int E){
  int e = blockIdx.x * blockDim.x + threadIdx.x;
  if (e < E) atomicAdd(&cnt[ei[E + e]], 1);
}

// K4: h = xn @ W_lin (bf16 MFMA) -> hq (bf16), fused a_src/a_dst dots from f32 acc.
__global__ __launch_bounds__(256) void k_hgemm(const unsigned short* __restrict__ xnq,
                                               const unsigned short* __restrict__ Wlt,
                                               const float* __restrict__ att_src,
                                               const float* __restrict__ att_dst,
                                               unsigned short* __restrict__ hq,
                                               float* __restrict__ asrc,
                                               float* __restrict__ adst, int N){
  int wid = threadIdx.x >> 6, lane = threadIdx.x & 63;
  int rb = blockIdx.x * 64 + wid * 16;
  int row = rb + (lane & 15);
  int rowc = row < N ? row : N - 1;
  int ksub = (lane >> 4) * 8;
  short8 a[4];
#pragma unroll
  for (int kb = 0; kb < 4; ++kb)
    a[kb] = *(const short8*)(xnq + (size_t)rowc * 128 + kb * 32 + ksub);
  f32x4 acc[8];
#pragma unroll
  for (int ct = 0; ct < 8; ++ct) acc[ct] = (f32x4){0.f, 0.f, 0.f, 0.f};
#pragma unroll
  for (int ct = 0; ct < 8; ++ct){
    int col = ct * 16 + (lane & 15);
#pragma unroll
    for (int kb = 0; kb < 4; ++kb){
      short8 bf = *(const short8*)(Wlt + (size_t)col * 128 + kb * 32 + ksub);
      acc[ct] = __builtin_amdgcn_mfma_f32_16x16x32_bf16(a[kb], bf, acc[ct], 0, 0, 0);
    }
  }
  int r0 = rb + (lane >> 4) * 4;
#pragma unroll
  for (int ct = 0; ct < 8; ++ct){
    int col = ct * 16 + (lane & 15);
#pragma unroll
    for (int j = 0; j < 4; ++j){
      int r = r0 + j;
      if (r < N) hq[(size_t)r * 128 + col] = bf16r(acc[ct][j]);
    }
  }
  float as_v[8], ad_v[8];
#pragma unroll
  for (int ct = 0; ct < 8; ++ct){
    int col = ct * 16 + (lane & 15);
    as_v[ct] = att_src[col];
    ad_v[ct] = att_dst[col];
  }
  float ps[4] = {0.f, 0.f, 0.f, 0.f}, pd[4] = {0.f, 0.f, 0.f, 0.f};
#pragma unroll
  for (int ct = 0; ct < 8; ++ct)
#pragma unroll
    for (int j = 0; j < 4; ++j){
      ps[j] += acc[ct][j] * as_v[ct];
      pd[j] += acc[ct][j] * ad_v[ct];
    }
#pragma unroll
  for (int m = 1; m < 16; m <<= 1)
#pragma unroll
    for (int j = 0; j < 4; ++j){
      ps[j] += __shfl_xor(ps[j], m);
      pd[j] += __shfl_xor(pd[j], m);
    }
  if ((lane & 15) == 0){
#pragma unroll
    for (int j = 0; j < 4; ++j){
      int r = r0 + j;
      if (r < N){ asrc[r] = ps[j]; adst[r] = pd[j]; }
    }
  }
}

// K5: exclusive scan of cnt -> start[0..N] (single block, chunked)
__global__ void k_scan(const int* __restrict__ cnt, int* __restrict__ start, int N){
  __shared__ int sd[1024];
  int t = threadIdx.x;
  int chunk = (N + 1023) / 1024;
  int lo = t * chunk;
  int hi = lo + chunk; if (hi > N) hi = N;
  int s = 0;
  for (int i = lo; i < hi; ++i) s += cnt[i];
  sd[t] = s;
  __syncthreads();
  for (int off = 1; off < 1024; off <<= 1){
    int v = (t >= off) ? sd[t - off] : 0;
    __syncthreads();
    sd[t] += v;
    __syncthreads();
  }
  int run = sd[t] - s;
  for (int i = lo; i < hi; ++i){ start[i] = run; run += cnt[i]; }
  if (t == 1023) start[N] = sd[1023];
}

// K6: fused edge logits + CSR scatter (2 edges per wave)
__global__ void k_edge_scatter(const float* __restrict__ ea, const int* __restrict__ ei,
                               const float* __restrict__ we, const float* __restrict__ asrc,
                               const float* __restrict__ adst, const int* __restrict__ start,
                               int* __restrict__ cursor, int* __restrict__ esrc_s,
                               float* __restrict__ ealpha_s, int E){
  int gw = (blockIdx.x * blockDim.x + threadIdx.x) >> 6;
  int lane = threadIdx.x & 63;
  int e = gw * 2 + (lane >> 5);
  int li = lane & 31;
  if (e >= E) return;
  float4 v = *(const float4*)(ea + (size_t)e * 128 + li * 4);
  float4 w = *(const float4*)(we + li * 4);
  float s = v.x * w.x + v.y * w.y + v.z * w.z + v.w * w.w;
#pragma unroll
  for (int m = 16; m; m >>= 1) s += __shfl_xor(s, m);
  if (li == 0){
    int sn = ei[e], dn = ei[E + e];
    float al = asrc[sn] + adst[dn] + s;
    al = al > 0.f ? al : NEG_SLOPE * al;
    int pos = atomicAdd(&cursor[dn], 1);
    int slot = start[dn] + pos;
    esrc_s[slot] = sn;
    ealpha_s[slot] = al;
  }
}

// K7: per-node softmax + weighted gather of hq[src] + residual + LN2 -> out, xn2q(bf16)
__global__ void k_agg(const float* __restrict__ x, const unsigned short* __restrict__ hq,
                      const int* __restrict__ start, const int* __restrict__ esrc_s,
                      const float* __restrict__ ealpha_s, const float* __restrict__ gat_bias,
                      const float* __restrict__ g2, const float* __restrict__ b2,
                      float* __restrict__ out, unsigned short* __restrict__ xn2q, int N){
  int n = (blockIdx.x * blockDim.x + threadIdx.x) >> 6;
  int lane = threadIdx.x & 63;
  if (n >= N) return;
  int beg = start[n], end = start[n + 1];
  float m = -1e30f;
  for (int i = beg + lane; i < end; i += 64) m = fmaxf(m, ealpha_s[i]);
  m = wred_max(m);
  float ds = 0.f;
  for (int i = beg + lane; i < end; i += 64) ds += __expf(ealpha_s[i] - m);
  ds = wred_sum(ds);
  float inv = (end > beg) ? 1.f / fmaxf(ds, 1e-16f) : 0.f;
  float a0 = 0.f, a1 = 0.f;
  int s = beg;
  for (; s + 2 <= end; s += 2){
    float c0 = __expf(ealpha_s[s] - m) * inv;
    float c1 = __expf(ealpha_s[s + 1] - m) * inv;
    int sn0 = esrc_s[s], sn1 = esrc_s[s + 1];
    unsigned int hv0 = *(const unsigned int*)(hq + (size_t)sn0 * 128 + lane * 2);
    unsigned int hv1 = *(const unsigned int*)(hq + (size_t)sn1 * 128 + lane * 2);
    a0 += c0 * bf2f(hv0 & 0xffffu) + c1 * bf2f(hv1 & 0xffffu);
    a1 += c0 * bf2f(hv0 >> 16)     + c1 * bf2f(hv1 >> 16);
  }
  if (s < end){
    float c = __expf(ealpha_s[s] - m) * inv;
    unsigned int hv = *(const unsigned int*)(hq + (size_t)esrc_s[s] * 128 + lane * 2);
    a0 += c * bf2f(hv & 0xffffu);
    a1 += c * bf2f(hv >> 16);
  }
  float2 xv  = *(const float2*)(x + (size_t)n * 128 + lane * 2);
  float2 gbv = *(const float2*)(gat_bias + lane * 2);
  float r0 = xv.x + a0 + gbv.x;
  float r1 = xv.y + a1 + gbv.y;
  float mu = wred_sum(r0 + r1) * (1.0f / 128.f);
  float d0 = r0 - mu, d1 = r1 - mu;
  float var = wred_sum(d0 * d0 + d1 * d1) * (1.0f / 128.f);
  float rstd = rsqrtf(var + 1e-5f);
  float2 gv = *(const float2*)(g2 + lane * 2);
  float2 bv = *(const float2*)(b2 + lane * 2);
  float o0 = d0 * rstd * gv.x + bv.x;
  float o1 = d1 * rstd * gv.y + bv.y;
  *(float2*)(out + (size_t)n * 128 + lane * 2) = make_float2(r0, r1);
  unsigned int p = (unsigned int)bf16r(o0) | ((unsigned int)bf16r(o1) << 16);
  *(unsigned int*)(xn2q + (size_t)n * 128 + lane * 2) = p;
}

// K8: fused FFN — 512 threads / 8 waves / 64 rows; hidden (64x512 bf16) in swizzled LDS.
// 64KB LDS -> 2 blocks/CU -> 16 waves/CU (4/SIMD) to hide L2 latency on B-loads.
__global__ __launch_bounds__(512) void k_ffn(const unsigned short* __restrict__ xn2q,
                                             const unsigned short* __restrict__ W1t,
                                             const unsigned short* __restrict__ W2t,
                                             const float* __restrict__ b1,
                                             const float* __restrict__ b2,
                                             float* __restrict__ out, int N){
  __shared__ unsigned short hid[64 * 512];  // row stride 1024B, XOR-swizzled
  int wid = threadIdx.x >> 6, lane = threadIdx.x & 63;
  int rg = wid >> 1;   // row group 0..3 (16 rows each)
  int ch = wid & 1;    // col half
  int rb = blockIdx.x * 64;
  int lr = rg * 16;
  int arow = rb + lr + (lane & 15);
  int arowc = arow < N ? arow : N - 1;
  int ksub = (lane >> 4) * 8;
  short8 a[4];
#pragma unroll
  for (int kb = 0; kb < 4; ++kb)
    a[kb] = *(const short8*)(xn2q + (size_t)arowc * 128 + kb * 32 + ksub);
  int lr0 = lr + (lane >> 4) * 4;
#pragma unroll 4
  for (int ct = 0; ct < 16; ++ct){
    int col = ch * 256 + ct * 16 + (lane & 15);
    f32x4 acc = {0.f, 0.f, 0.f, 0.f};
#pragma unroll
    for (int kb = 0; kb < 4; ++kb){
      short8 bf = *(const short8*)(W1t + (size_t)col * 128 + kb * 32 + ksub);
      acc = __builtin_amdgcn_mfma_f32_16x16x32_bf16(a[kb], bf, acc, 0, 0, 0);
    }
    float bias = b1[col];
#pragma unroll
    for (int j = 0; j < 4; ++j){
      float v = acc[j] + bias;
      v = v > 0.f ? v : 0.f;
      int row = lr0 + j;
      int byte = (col * 2) ^ ((row & 7) << 4);
      *(unsigned short*)((char*)hid + row * 1024 + byte) = bf16r(v);
    }
  }
  __syncthreads();
  f32x4 acc2[4];
#pragma unroll
  for (int ct = 0; ct < 4; ++ct) acc2[ct] = (f32x4){0.f, 0.f, 0.f, 0.f};
  int arow2 = lr + (lane & 15);
#pragma unroll 2
  for (int kb = 0; kb < 16; ++kb){
    int kbyte = (kb * 32 + ksub) * 2;
    int sb = kbyte ^ ((arow2 & 7) << 4);
    short8 af = *(const short8*)((const char*)hid + arow2 * 1024 + sb);
#pragma unroll
    for (int ct = 0; ct < 4; ++ct){
      int col = ch * 64 + ct * 16 + (lane & 15);
      short8 bf = *(const short8*)(W2t + (size_t)col * 512 + kb * 32 + ksub);
      acc2[ct] = __builtin_amdgcn_mfma_f32_16x16x32_bf16(af, bf, acc2[ct], 0, 0, 0);
    }
  }
  int r0 = rb + lr0;
#pragma unroll
  for (int ct = 0; ct < 4; ++ct){
    int col = ch * 64 + ct * 16 + (lane & 15);
    float bias = b2[col];
#pragma unroll
    for (int j = 0; j < 4; ++j){
      int row = r0 + j;
      if (row < N) out[(size_t)row * 128 + col] += acc2[ct][j] + bias;
    }
  }
}

extern "C" void kernel_launch(void* const* d_in, const int* in_sizes, int n_in,
                              void* d_out, int out_size, void* d_ws, size_t ws_size,
                              hipStream_t stream){
  const float* x        = (const float*)d_in[0];
  const int*   ei       = (const int*)  d_in[1];
  const float* ea       = (const float*)d_in[2];
  const float* ln1_g    = (const float*)d_in[3];
  const float* ln1_b    = (const float*)d_in[4];
  const float* W_lin    = (const float*)d_in[5];
  const float* att_src  = (const float*)d_in[6];
  const float* att_dst  = (const float*)d_in[7];
  const float* W_edge   = (const float*)d_in[8];
  const float* att_edge = (const float*)d_in[9];
  const float* gat_bias = (const float*)d_in[10];
  const float* ln2_g    = (const float*)d_in[11];
  const float* ln2_b    = (const float*)d_in[12];
  const float* W1       = (const float*)d_in[13];
  const float* b1       = (const float*)d_in[14];
  const float* W2       = (const float*)d_in[15];
  const float* b2       = (const float*)d_in[16];

  const int N = in_sizes[0] / 128;
  const int E = in_sizes[2] / 128;
  float* out = (float*)d_out;

  char* p = (char*)d_ws;
  auto carve = [&](size_t bytes) -> char* {
    char* r = p; p += (bytes + 255) & ~(size_t)255; return r;
  };
  unsigned short* xnq      = (unsigned short*)carve((size_t)N * 128 * 2); // reused as xn2q
  unsigned short* hq       = (unsigned short*)carve((size_t)N * 128 * 2);
  float*          asrc     = (float*)carve((size_t)N * 4);
  float*          adst     = (float*)carve((size_t)N * 4);
  float*          ealpha_s = (float*)carve((size_t)E * 4);
  int*            esrc_s   = (int*)carve((size_t)E * 4);
  int*            cnt      = (int*)carve((size_t)N * 4);
  int*            cursor   = (int*)carve((size_t)N * 4);
  int*            start    = (int*)carve((size_t)(N + 1) * 4);
  unsigned short* Wlt      = (unsigned short*)carve(128 * 128 * 2);
  unsigned short* W1t      = (unsigned short*)carve(512 * 128 * 2);
  unsigned short* W2t      = (unsigned short*)carve(128 * 512 * 2);
  float*          we       = (float*)carve(128 * 4);
  unsigned short* xn2q     = xnq;  // alias: xnq dead after k_hgemm

  int nwb = (N + 3) / 4;  // 4 rows per 256-thread block (wave per row)
  k_ln1<<<nwb, 256, 0, stream>>>(x, ln1_g, ln1_b, xnq, N);
  k_prep<<<(128*128 + 512*128 + 128*512 + 128 + 255) / 256, 256, 0, stream>>>(
      W_lin, W1, W2, W_edge, att_edge, Wlt, W1t, W2t, we, cnt, cursor, N);
  k_count<<<(E + 255) / 256, 256, 0, stream>>>(ei, cnt, E);
  k_hgemm<<<(N + 63) / 64, 256, 0, stream>>>(xnq, Wlt, att_src, att_dst, hq, asrc, adst, N);
  k_scan<<<1, 1024, 0, stream>>>(cnt, start, N);
  k_edge_scatter<<<(E + 7) / 8, 256, 0, stream>>>(ea, ei, we, asrc, adst, start, cursor,
                                                  esrc_s, ealpha_s, E);
  k_agg<<<nwb, 256, 0, stream>>>(x, hq, start, esrc_s, ealpha_s, gat_bias, ln2_g, ln2_b,
                                 out, xn2q, N);
  k_ffn<<<(N + 63) / 64, 512, 0, stream>>>(xn2q, W1t, W2t, b1, b2, out, N);
}

// Round 4
// 344.355 us; speedup vs baseline: 1.4300x; 1.2725x over previous
//
#include <hip/hip_runtime.h>

#define D 128
#define NEG_SLOPE 0.2f

typedef __attribute__((ext_vector_type(8))) short short8;
typedef __attribute__((ext_vector_type(4))) float f32x4;

__device__ __forceinline__ float wred_sum(float v){
#pragma unroll
  for (int m = 32; m; m >>= 1) v += __shfl_xor(v, m);
  return v;
}
__device__ __forceinline__ int wred_sumi(int v){
#pragma unroll
  for (int m = 32; m; m >>= 1) v += __shfl_xor(v, m);
  return v;
}
__device__ __forceinline__ float wred_max(float v){
#pragma unroll
  for (int m = 32; m; m >>= 1) v = fmaxf(v, __shfl_xor(v, m));
  return v;
}
__device__ __forceinline__ unsigned short bf16r(float f){
  unsigned int u = __float_as_uint(f);
  u += 0x7fffu + ((u >> 16) & 1u);
  return (unsigned short)(u >> 16);
}
__device__ __forceinline__ float bf2f(unsigned int hi16){
  return __uint_as_float(hi16 << 16);
}

// K1: xn = LN(x, ln1) -> bf16 (wave/row); zero cnt (needed before k_prep counts)
__global__ void k_ln1(const float* __restrict__ x, const float* __restrict__ g,
                      const float* __restrict__ b, unsigned short* __restrict__ xnq,
                      int* __restrict__ cnt, int N){
  int gid = blockIdx.x * blockDim.x + threadIdx.x;
  if (gid < N) cnt[gid] = 0;
  int w = gid >> 6;
  int lane = threadIdx.x & 63;
  if (w >= N) return;
  float2 v = *(const float2*)(x + (size_t)w * D + lane * 2);
  float mu = wred_sum(v.x + v.y) * (1.0f / D);
  float d0 = v.x - mu, d1 = v.y - mu;
  float var = wred_sum(d0 * d0 + d1 * d1) * (1.0f / D);
  float rstd = rsqrtf(var + 1e-5f);
  float2 gv = *(const float2*)(g + lane * 2);
  float2 bv = *(const float2*)(b + lane * 2);
  float o0 = d0 * rstd * gv.x + bv.x;
  float o1 = d1 * rstd * gv.y + bv.y;
  unsigned int p = (unsigned int)bf16r(o0) | ((unsigned int)bf16r(o1) << 16);
  *(unsigned int*)(xnq + (size_t)w * D + lane * 2) = p;
}

// K2: weight prep (bf16 transposes + we = W_edge@att_edge) + grid-stride degree count
__global__ void k_prep(const float* __restrict__ W_lin, const float* __restrict__ W1,
                       const float* __restrict__ W2, const float* __restrict__ W_edge,
                       const float* __restrict__ att_edge, const int* __restrict__ ei,
                       unsigned short* __restrict__ Wlt, unsigned short* __restrict__ W1t,
                       unsigned short* __restrict__ W2t, float* __restrict__ we,
                       int* __restrict__ cnt, int E){
  int t = blockIdx.x * blockDim.x + threadIdx.x;
  if (t < 128 * 128){
    int c = t >> 7, k = t & 127;
    Wlt[t] = bf16r(W_lin[k * 128 + c]);
  } else if (t < 128 * 128 + 512 * 128){
    int u = t - 128 * 128; int c = u >> 7, k = u & 127;
    W1t[u] = bf16r(W1[k * 512 + c]);
  } else if (t < 128 * 128 + 512 * 128 + 128 * 512){
    int u = t - (128 * 128 + 512 * 128); int c = u >> 9, k = u & 511;
    W2t[u] = bf16r(W2[k * 128 + c]);
  } else {
    int u = t - (128 * 128 + 512 * 128 + 128 * 512);
    if (u < 128){
      float s = 0.f;
      for (int j = 0; j < 128; ++j) s += W_edge[u * 128 + j] * att_edge[j];
      we[u] = s;
    }
  }
  int stride = gridDim.x * blockDim.x;
  for (int e = t; e < E; e += stride) atomicAdd(&cnt[ei[E + e]], 1);
}

// K3: h = xn @ W_lin (bf16 MFMA) -> hq (bf16), fused a_src/a_dst dots from f32 acc.
__global__ __launch_bounds__(256) void k_hgemm(const unsigned short* __restrict__ xnq,
                                               const unsigned short* __restrict__ Wlt,
                                               const float* __restrict__ att_src,
                                               const float* __restrict__ att_dst,
                                               unsigned short* __restrict__ hq,
                                               float* __restrict__ asrc,
                                               float* __restrict__ adst, int N){
  int wid = threadIdx.x >> 6, lane = threadIdx.x & 63;
  int rb = blockIdx.x * 64 + wid * 16;
  int row = rb + (lane & 15);
  int rowc = row < N ? row : N - 1;
  int ksub = (lane >> 4) * 8;
  short8 a[4];
#pragma unroll
  for (int kb = 0; kb < 4; ++kb)
    a[kb] = *(const short8*)(xnq + (size_t)rowc * 128 + kb * 32 + ksub);
  f32x4 acc[8];
#pragma unroll
  for (int ct = 0; ct < 8; ++ct) acc[ct] = (f32x4){0.f, 0.f, 0.f, 0.f};
#pragma unroll
  for (int ct = 0; ct < 8; ++ct){
    int col = ct * 16 + (lane & 15);
#pragma unroll
    for (int kb = 0; kb < 4; ++kb){
      short8 bf = *(const short8*)(Wlt + (size_t)col * 128 + kb * 32 + ksub);
      acc[ct] = __builtin_amdgcn_mfma_f32_16x16x32_bf16(a[kb], bf, acc[ct], 0, 0, 0);
    }
  }
  int r0 = rb + (lane >> 4) * 4;
#pragma unroll
  for (int ct = 0; ct < 8; ++ct){
    int col = ct * 16 + (lane & 15);
#pragma unroll
    for (int j = 0; j < 4; ++j){
      int r = r0 + j;
      if (r < N) hq[(size_t)r * 128 + col] = bf16r(acc[ct][j]);
    }
  }
  float as_v[8], ad_v[8];
#pragma unroll
  for (int ct = 0; ct < 8; ++ct){
    int col = ct * 16 + (lane & 15);
    as_v[ct] = att_src[col];
    ad_v[ct] = att_dst[col];
  }
  float ps[4] = {0.f, 0.f, 0.f, 0.f}, pd[4] = {0.f, 0.f, 0.f, 0.f};
#pragma unroll
  for (int ct = 0; ct < 8; ++ct)
#pragma unroll
    for (int j = 0; j < 4; ++j){
      ps[j] += acc[ct][j] * as_v[ct];
      pd[j] += acc[ct][j] * ad_v[ct];
    }
#pragma unroll
  for (int m = 1; m < 16; m <<= 1)
#pragma unroll
    for (int j = 0; j < 4; ++j){
      ps[j] += __shfl_xor(ps[j], m);
      pd[j] += __shfl_xor(pd[j], m);
    }
  if ((lane & 15) == 0){
#pragma unroll
    for (int j = 0; j < 4; ++j){
      int r = r0 + j;
      if (r < N){ asrc[r] = ps[j]; adst[r] = pd[j]; }
    }
  }
}

// K4: per-block sums of cnt (256 els/block)
__global__ void k_bsum(const int* __restrict__ cnt, int* __restrict__ bsum, int N){
  int t = threadIdx.x;
  int i = blockIdx.x * 256 + t;
  int v = (i < N) ? cnt[i] : 0;
  v = wred_sumi(v);
  __shared__ int ws[4];
  if ((t & 63) == 0) ws[t >> 6] = v;
  __syncthreads();
  if (t == 0) bsum[blockIdx.x] = ws[0] + ws[1] + ws[2] + ws[3];
}

// K5: per-block exclusive scan + global offset -> start[0..N], cursor[n]=start[n]
__global__ void k_escan(const int* __restrict__ cnt, const int* __restrict__ bsum,
                        int* __restrict__ start, int* __restrict__ cursor, int N){
  int b = blockIdx.x, t = threadIdx.x;
  __shared__ int s_off;
  if (t < 64){
    int acc = 0;
    for (int j = t; j < b; j += 64) acc += bsum[j];
    acc = wred_sumi(acc);
    if (t == 0) s_off = acc;
  }
  int i = b * 256 + t;
  int c = (i < N) ? cnt[i] : 0;
  __shared__ int sd[256];
  sd[t] = c;
  __syncthreads();
  for (int off = 1; off < 256; off <<= 1){
    int v = (t >= off) ? sd[t - off] : 0;
    __syncthreads();
    sd[t] += v;
    __syncthreads();
  }
  int st = s_off + sd[t] - c;   // exclusive prefix
  if (i <= N) start[i] = st;
  if (i < N) cursor[i] = st;
}

// K6: fused edge logits + CSR scatter (2 edges per wave), packed (src, alpha) int2
__global__ void k_edge_scatter(const float* __restrict__ ea, const int* __restrict__ ei,
                               const float* __restrict__ we, const float* __restrict__ asrc,
                               const float* __restrict__ adst, int* __restrict__ cursor,
                               int2* __restrict__ esa, int E){
  int gw = (blockIdx.x * blockDim.x + threadIdx.x) >> 6;
  int lane = threadIdx.x & 63;
  int e = gw * 2 + (lane >> 5);
  int li = lane & 31;
  if (e >= E) return;
  float4 v = *(const float4*)(ea + (size_t)e * 128 + li * 4);
  float4 w = *(const float4*)(we + li * 4);
  float s = v.x * w.x + v.y * w.y + v.z * w.z + v.w * w.w;
#pragma unroll
  for (int m = 16; m; m >>= 1) s += __shfl_xor(s, m);
  if (li == 0){
    int sn = ei[e], dn = ei[E + e];
    float al = asrc[sn] + adst[dn] + s;
    al = al > 0.f ? al : NEG_SLOPE * al;
    int slot = atomicAdd(&cursor[dn], 1);
    esa[slot] = make_int2(sn, __float_as_int(al));
  }
}

// K7: per-node softmax (single-pass denom) + weighted gather + residual + LN2
__global__ void k_agg(const float* __restrict__ x, const unsigned short* __restrict__ hq,
                      const int* __restrict__ start, const int2* __restrict__ esa,
                      const float* __restrict__ gat_bias,
                      const float* __restrict__ g2, const float* __restrict__ b2,
                      float* __restrict__ out, unsigned short* __restrict__ xn2q, int N){
  int n = (blockIdx.x * blockDim.x + threadIdx.x) >> 6;
  int lane = threadIdx.x & 63;
  if (n >= N) return;
  int beg = start[n], end = start[n + 1];
  float m = -1e30f;
  for (int i = beg + lane; i < end; i += 64) m = fmaxf(m, __int_as_float(esa[i].y));
  m = wred_max(m);
  float ds = 0.f, a0 = 0.f, a1 = 0.f;
#pragma unroll 2
  for (int s = beg; s < end; ++s){
    int2 ev = esa[s];                       // uniform address -> broadcast
    float ex = __expf(__int_as_float(ev.y) - m);
    ds += ex;
    unsigned int hv = *(const unsigned int*)(hq + (size_t)ev.x * 128 + lane * 2);
    a0 += ex * bf2f(hv & 0xffffu);
    a1 += ex * bf2f(hv >> 16);
  }
  float inv = (end > beg) ? 1.f / fmaxf(ds, 1e-16f) : 0.f;
  a0 *= inv; a1 *= inv;
  float2 xv  = *(const float2*)(x + (size_t)n * 128 + lane * 2);
  float2 gbv = *(const float2*)(gat_bias + lane * 2);
  float r0 = xv.x + a0 + gbv.x;
  float r1 = xv.y + a1 + gbv.y;
  float mu = wred_sum(r0 + r1) * (1.0f / 128.f);
  float d0 = r0 - mu, d1 = r1 - mu;
  float var = wred_sum(d0 * d0 + d1 * d1) * (1.0f / 128.f);
  float rstd = rsqrtf(var + 1e-5f);
  float2 gv = *(const float2*)(g2 + lane * 2);
  float2 bv = *(const float2*)(b2 + lane * 2);
  float o0 = d0 * rstd * gv.x + bv.x;
  float o1 = d1 * rstd * gv.y + bv.y;
  *(float2*)(out + (size_t)n * 128 + lane * 2) = make_float2(r0, r1);
  unsigned int p = (unsigned int)bf16r(o0) | ((unsigned int)bf16r(o1) << 16);
  *(unsigned int*)(xn2q + (size_t)n * 128 + lane * 2) = p;
}

// K8: fused FFN — 512 threads / 8 waves / 64 rows; hidden (64x512 bf16) in swizzled LDS.
__global__ __launch_bounds__(512) void k_ffn(const unsigned short* __restrict__ xn2q,
                                             const unsigned short* __restrict__ W1t,
                                             const unsigned short* __restrict__ W2t,
                                             const float* __restrict__ b1,
                                             const float* __restrict__ b2,
                                             float* __restrict__ out, int N){
  __shared__ unsigned short hid[64 * 512];  // row stride 1024B, XOR-swizzled
  int wid = threadIdx.x >> 6, lane = threadIdx.x & 63;
  int rg = wid >> 1;   // row group 0..3 (16 rows each)
  int ch = wid & 1;    // col half
  int rb = blockIdx.x * 64;
  int lr = rg * 16;
  int arow = rb + lr + (lane & 15);
  int arowc = arow < N ? arow : N - 1;
  int ksub = (lane >> 4) * 8;
  short8 a[4];
#pragma unroll
  for (int kb = 0; kb < 4; ++kb)
    a[kb] = *(const short8*)(xn2q + (size_t)arowc * 128 + kb * 32 + ksub);
  int lr0 = lr + (lane >> 4) * 4;
#pragma unroll 4
  for (int ct = 0; ct < 16; ++ct){
    int col = ch * 256 + ct * 16 + (lane & 15);
    f32x4 acc = {0.f, 0.f, 0.f, 0.f};
#pragma unroll
    for (int kb = 0; kb < 4; ++kb){
      short8 bf = *(const short8*)(W1t + (size_t)col * 128 + kb * 32 + ksub);
      acc = __builtin_amdgcn_mfma_f32_16x16x32_bf16(a[kb], bf, acc, 0, 0, 0);
    }
    float bias = b1[col];
#pragma unroll
    for (int j = 0; j < 4; ++j){
      float v = acc[j] + bias;
      v = v > 0.f ? v : 0.f;
      int row = lr0 + j;
      int byte = (col * 2) ^ ((row & 7) << 4);
      *(unsigned short*)((char*)hid + row * 1024 + byte) = bf16r(v);
    }
  }
  __syncthreads();
  f32x4 acc2[4];
#pragma unroll
  for (int ct = 0; ct < 4; ++ct) acc2[ct] = (f32x4){0.f, 0.f, 0.f, 0.f};
  int arow2 = lr + (lane & 15);
#pragma unroll 2
  for (int kb = 0; kb < 16; ++kb){
    int kbyte = (kb * 32 + ksub) * 2;
    int sb = kbyte ^ ((arow2 & 7) << 4);
    short8 af = *(const short8*)((const char*)hid + arow2 * 1024 + sb);
#pragma unroll
    for (int ct = 0; ct < 4; ++ct){
      int col = ch * 64 + ct * 16 + (lane & 15);
      short8 bf = *(const short8*)(W2t + (size_t)col * 512 + kb * 32 + ksub);
      acc2[ct] = __builtin_amdgcn_mfma_f32_16x16x32_bf16(af, bf, acc2[ct], 0, 0, 0);
    }
  }
  int r0 = rb + lr0;
#pragma unroll
  for (int ct = 0; ct < 4; ++ct){
    int col = ch * 64 + ct * 16 + (lane & 15);
    float bias = b2[col];
#pragma unroll
    for (int j = 0; j < 4; ++j){
      int row = r0 + j;
      if (row < N) out[(size_t)row * 128 + col] += acc2[ct][j] + bias;
    }
  }
}

extern "C" void kernel_launch(void* const* d_in, const int* in_sizes, int n_in,
                              void* d_out, int out_size, void* d_ws, size_t ws_size,
                              hipStream_t stream){
  const float* x        = (const float*)d_in[0];
  const int*   ei       = (const int*)  d_in[1];
  const float* ea       = (const float*)d_in[2];
  const float* ln1_g    = (const float*)d_in[3];
  const float* ln1_b    = (const float*)d_in[4];
  const float* W_lin    = (const float*)d_in[5];
  const float* att_src  = (const float*)d_in[6];
  const float* att_dst  = (const float*)d_in[7];
  const float* W_edge   = (const float*)d_in[8];
  const float* att_edge = (const float*)d_in[9];
  const float* gat_bias = (const float*)d_in[10];
  const float* ln2_g    = (const float*)d_in[11];
  const float* ln2_b    = (const float*)d_in[12];
  const float* W1       = (const float*)d_in[13];
  const float* b1       = (const float*)d_in[14];
  const float* W2       = (const float*)d_in[15];
  const float* b2       = (const float*)d_in[16];

  const int N = in_sizes[0] / 128;
  const int E = in_sizes[2] / 128;
  const int NB = (N + 255) / 256;
  float* out = (float*)d_out;

  char* p = (char*)d_ws;
  auto carve = [&](size_t bytes) -> char* {
    char* r = p; p += (bytes + 255) & ~(size_t)255; return r;
  };
  unsigned short* xnq      = (unsigned short*)carve((size_t)N * 128 * 2); // reused as xn2q
  unsigned short* hq       = (unsigned short*)carve((size_t)N * 128 * 2);
  float*          asrc     = (float*)carve((size_t)N * 4);
  float*          adst     = (float*)carve((size_t)N * 4);
  int2*           esa      = (int2*)carve((size_t)E * 8);
  int*            cnt      = (int*)carve((size_t)N * 4);
  int*            cursor   = (int*)carve((size_t)N * 4);
  int*            start    = (int*)carve((size_t)(N + 1) * 4);
  int*            bsum     = (int*)carve((size_t)NB * 4);
  unsigned short* Wlt      = (unsigned short*)carve(128 * 128 * 2);
  unsigned short* W1t      = (unsigned short*)carve(512 * 128 * 2);
  unsigned short* W2t      = (unsigned short*)carve(128 * 512 * 2);
  float*          we       = (float*)carve(128 * 4);
  unsigned short* xn2q     = xnq;  // alias: xnq dead after k_hgemm

  int nwb = (N + 3) / 4;  // 4 rows per 256-thread block (wave per row)
  k_ln1<<<nwb, 256, 0, stream>>>(x, ln1_g, ln1_b, xnq, cnt, N);
  k_prep<<<(E + 255) / 256, 256, 0, stream>>>(W_lin, W1, W2, W_edge, att_edge, ei,
                                              Wlt, W1t, W2t, we, cnt, E);
  k_hgemm<<<(N + 63) / 64, 256, 0, stream>>>(xnq, Wlt, att_src, att_dst, hq, asrc, adst, N);
  k_bsum<<<NB, 256, 0, stream>>>(cnt, bsum, N);
  k_escan<<<NB, 256, 0, stream>>>(cnt, bsum, start, cursor, N);
  k_edge_scatter<<<(E + 7) / 8, 256, 0, stream>>>(ea, ei, we, asrc, adst, cursor, esa, E);
  k_agg<<<nwb, 256, 0, stream>>>(x, hq, start, esa, gat_bias, ln2_g, ln2_b, out, xn2q, N);
  k_ffn<<<(N + 63) / 64, 512, 0, stream>>>(xn2q, W1t, W2t, b1, b2, out, N);
}